// Round 7
// baseline (414.030 us; speedup 1.0000x reference)
//
#include <hip/hip_runtime.h>
#include <hip/hip_bf16.h>

// Problem constants (match reference setup_inputs)
#define NN 30000      // nodes
#define NE 600000     // edges
#define DD 128        // feature dim
#define RR 7          // relations
#define GG 16         // graphs
#define LL 3          // layers

#define NB64 ((NN + 63) / 64)   // 469 buckets of 64 nodes
#define NROW (NB64 * 64)        // 30016 padded rows
#define MS   (RR * DD)          // 896 msg row stride

typedef short bf16x8 __attribute__((ext_vector_type(8)));  // 8 bf16 = 4 VGPRs
typedef float f32x4  __attribute__((ext_vector_type(4)));

// ---- bf16 helpers ----------------------------------------------------------
__device__ __forceinline__ unsigned short f2bf(float f) {
    unsigned u = __float_as_uint(f);
    unsigned r = (u + 0x7fffu + ((u >> 16) & 1u)) >> 16;
    return (unsigned short)r;
}
// packed f32x2 -> bf16x2 (v_cvt_pk_bf16_f32 on gfx950)
__device__ __forceinline__ ushort2 pk2bf(float a, float b) {
    __hip_bfloat162 t = __float22bfloat162_rn(make_float2(a, b));
    return *(ushort2*)&t;
}

// async global->LDS, 16B per lane; LDS dest = wave-uniform base + lane*16
__device__ __forceinline__ void gl_lds16(const void* g, void* l) {
    __builtin_amdgcn_global_load_lds(
        (const __attribute__((address_space(1))) void*)g,
        (__attribute__((address_space(3))) void*)l, 16, 0, 0);
}

// ---------------------------------------------------------------------------
// Weight pack: Bw2[l][kc][n][k'] (bf16) with B[k][n] = Wr[l][k][n] (k<896)
// else Wl[l][k-896][n];  k = kc*128 + k'. Also zeros bcnt (runs before hist).
// ---------------------------------------------------------------------------
__global__ __launch_bounds__(256) void pack_weights(
    const float* __restrict__ Wl,   // L x 128 x 128
    const float* __restrict__ Wr,   // L x 896 x 128
    unsigned short* __restrict__ Bw2,// L x 8 x 128 x 128
    int* __restrict__ bcnt)
{
    int t = blockIdx.x * 256 + threadIdx.x;
    if (t < NB64 * 16) bcnt[t] = 0;
    if (t >= LL * 8 * DD * DD) return;
    int kp = t & 127;              // k'
    int n  = (t >> 7) & 127;
    int kc = (t >> 14) & 7;
    int l  = t >> 17;
    int k  = kc * 128 + kp;
    float v;
    if (k < MS) v = Wr[(size_t)l * MS * DD + (size_t)k * DD + n];
    else        v = Wl[(size_t)l * DD * DD + (size_t)(k - MS) * DD + n];
    Bw2[(size_t)l * 8 * DD * DD + (size_t)kc * DD * DD + n * DD + kp] = f2bf(v);
}

// x (fp32) -> bf16; block 0 also zeros gf (16x128 floats)
__global__ __launch_bounds__(256) void convert_bf16(
    const float* __restrict__ in, unsigned short* __restrict__ out,
    float* __restrict__ gf, int n4)
{
    int i = blockIdx.x * 256 + threadIdx.x;
    if (blockIdx.x == 0) {
#pragma unroll
        for (int j = 0; j < 8; ++j) gf[threadIdx.x + j * 256] = 0.f;
    }
    if (i >= n4) return;
    float4 v = ((const float4*)in)[i];
    ushort2 lo = pk2bf(v.x, v.y);
    ushort2 hi = pk2bf(v.z, v.w);
    ((ushort4*)out)[i] = make_ushort4(lo.x, lo.y, hi.x, hi.y);
}

// ---------------------------------------------------------------------------
// Bucketed edge sort. Bucket = 64 dest nodes; within bucket sort by
// key = (dest&63)<<3 | rel  (512 bins). Emits meta=(src*128, ew) grouped by
// (dest,rel) and start2[node*8 + r] segment pointers (slot 7 = end).
// ---------------------------------------------------------------------------
__global__ __launch_bounds__(256) void bucket_hist(
    const int* __restrict__ node_out, int* __restrict__ bcnt, int E)
{
    int e = blockIdx.x * 256 + threadIdx.x;
    if (e < E) atomicAdd(&bcnt[(node_out[e] >> 6) * 16], 1);
}

__global__ __launch_bounds__(512) void bucket_scan(
    const int* __restrict__ bcnt, int* __restrict__ bstart,
    int* __restrict__ bcur, int nb)
{
    __shared__ int s[512];
    int t = threadIdx.x;
    int v = (t < nb) ? bcnt[t * 16] : 0;
    s[t] = v;
    __syncthreads();
#pragma unroll
    for (int off = 1; off < 512; off <<= 1) {
        int u = (t >= off) ? s[t - off] : 0;
        __syncthreads();
        s[t] += u;
        __syncthreads();
    }
    if (t <= nb) {
        int excl = s[t] - v;
        bstart[t] = excl;
        if (t < nb) bcur[t * 16] = excl;
    }
}

// pack.x = (out&63)<<21 | rel<<18 | src   (src < 2^18)
__global__ __launch_bounds__(256) void bucket_scatter(
    const int* __restrict__ node_in,
    const int* __restrict__ node_out,
    const int* __restrict__ relation,
    const float* __restrict__ ew,
    int* __restrict__ bcur,
    int2* __restrict__ tmp,
    int E)
{
    int e = blockIdx.x * 256 + threadIdx.x;
    if (e >= E) return;
    int o = node_out[e];
    int pos = atomicAdd(&bcur[(o >> 6) * 16], 1);
    tmp[pos] = make_int2(((o & 63) << 21) | (relation[e] << 18) | node_in[e],
                         __float_as_int(ew[e]));
}

__global__ __launch_bounds__(256) void bucket_sort(
    const int2* __restrict__ tmp,
    const int* __restrict__ bstart,
    int2* __restrict__ meta,
    int* __restrict__ start2,   // NROW*8
    int N)
{
    __shared__ int hist[512];
    __shared__ int excl[512];
    __shared__ int cur[512];
    __shared__ int ssum[256];
    const int b = blockIdx.x;
    const int t = threadIdx.x;
    const int s0 = bstart[b];
    const int s1 = bstart[b + 1];

    hist[t] = 0; hist[t + 256] = 0;
    __syncthreads();
    for (int i = s0 + t; i < s1; i += 256)
        atomicAdd(&hist[((unsigned)tmp[i].x) >> 18], 1);
    __syncthreads();

    // 512-wide exclusive scan via 256 threads (2 elems each)
    int a0 = hist[2 * t], a1 = hist[2 * t + 1];
    ssum[t] = a0 + a1;
    __syncthreads();
#pragma unroll
    for (int off = 1; off < 256; off <<= 1) {
        int u = (t >= off) ? ssum[t - off] : 0;
        __syncthreads();
        ssum[t] += u;
        __syncthreads();
    }
    int base = (t == 0) ? 0 : ssum[t - 1];
    excl[2 * t] = base;
    excl[2 * t + 1] = base + a0;
    cur[2 * t] = s0 + base;
    cur[2 * t + 1] = s0 + base + a0;
    __syncthreads();

    // start2: key j = dl*8 + r; rel-7 bin has count 0, so excl[dl*8+7] == end
    {
        int node0 = b * 64 + (t >> 3) * 2;     // t covers 2 keys: reuse 2t,2t+1
        // simpler: each thread writes its 2 keys
        int k0 = 2 * t, k1 = 2 * t + 1;
        int n0 = b * 64 + (k0 >> 3), n1 = b * 64 + (k1 >> 3);
        if (n0 < N) start2[n0 * 8 + (k0 & 7)] = s0 + excl[k0];
        if (n1 < N) start2[n1 * 8 + (k1 & 7)] = s0 + excl[k1];
        (void)node0;
    }
    __syncthreads();

    for (int i = s0 + t; i < s1; i += 256) {
        int2 m = tmp[i];
        int key = ((unsigned)m.x) >> 18;
        int pos = atomicAdd(&cur[key], 1);
        int src = m.x & 0x3ffff;
        meta[pos] = make_int2(src << 7, m.y);   // src*128 element offset in hb
    }
}

// ---------------------------------------------------------------------------
// aggregate_msg: msg[d][r][:] = sum_{e in seg(d,r)} ew_e * h[src_e][:]
// One 64-lane wave per dest node; lane owns 2 columns. Gathers hit the 7.7 MB
// h buffer (L2-resident). Sequential 256 B writes per (d,r).
// ---------------------------------------------------------------------------
__global__ __launch_bounds__(256) void aggregate_msg(
    const unsigned short* __restrict__ hb,   // NROW x 128 bf16
    const int* __restrict__ start2,          // NROW*8
    const int2* __restrict__ meta,           // E
    unsigned short* __restrict__ msg,        // NROW x 896 bf16
    int N)
{
    int wid = (blockIdx.x * 256 + threadIdx.x) >> 6;
    int lane = threadIdx.x & 63;
    if (wid >= N) return;

    unsigned short* mrow = msg + (size_t)wid * MS + lane * 2;
#pragma unroll
    for (int r = 0; r < RR; ++r) {
        int e0 = start2[wid * 8 + r];
        int e1 = start2[wid * 8 + r + 1];
        float ax = 0.f, ay = 0.f;
        int e = e0;
        for (; e + 4 <= e1; e += 4) {
            int2 m0 = meta[e + 0];
            int2 m1 = meta[e + 1];
            int2 m2 = meta[e + 2];
            int2 m3 = meta[e + 3];
            unsigned u0 = *(const unsigned*)(hb + m0.x + lane * 2);
            unsigned u1 = *(const unsigned*)(hb + m1.x + lane * 2);
            unsigned u2 = *(const unsigned*)(hb + m2.x + lane * 2);
            unsigned u3 = *(const unsigned*)(hb + m3.x + lane * 2);
            float w0 = __int_as_float(m0.y), w1 = __int_as_float(m1.y);
            float w2 = __int_as_float(m2.y), w3 = __int_as_float(m3.y);
            ax = fmaf(w0, __uint_as_float(u0 << 16), ax);
            ay = fmaf(w0, __uint_as_float(u0 & 0xffff0000u), ay);
            ax = fmaf(w1, __uint_as_float(u1 << 16), ax);
            ay = fmaf(w1, __uint_as_float(u1 & 0xffff0000u), ay);
            ax = fmaf(w2, __uint_as_float(u2 << 16), ax);
            ay = fmaf(w2, __uint_as_float(u2 & 0xffff0000u), ay);
            ax = fmaf(w3, __uint_as_float(u3 << 16), ax);
            ay = fmaf(w3, __uint_as_float(u3 & 0xffff0000u), ay);
        }
        for (; e < e1; ++e) {
            int2 m = meta[e];
            unsigned u = *(const unsigned*)(hb + m.x + lane * 2);
            float wt = __int_as_float(m.y);
            ax = fmaf(wt, __uint_as_float(u << 16), ax);
            ay = fmaf(wt, __uint_as_float(u & 0xffff0000u), ay);
        }
        *(ushort2*)(mrow + r * DD) = pk2bf(ax, ay);
    }
}

// ---------------------------------------------------------------------------
// gemm2: h' = relu([msg | h] (N x 1024) @ Bw2 (1024 x 128) + br + bl)
// Block: 64 rows x 128 cols, 256 threads = 4 waves. K looped in 8 chunks of
// 128, single-buffered LDS staged via global_load_lds width=16.
// ---------------------------------------------------------------------------
__global__ __launch_bounds__(256) void gemm2(
    const unsigned short* __restrict__ msg,  // NROW x 896 bf16
    const unsigned short* __restrict__ hb,   // NROW x 128 bf16
    const unsigned short* __restrict__ Bw2l, // 8 x 128 x 128 bf16
    const float* __restrict__ br,            // 128
    const float* __restrict__ bl,            // 128
    unsigned short* __restrict__ out_bf16,   // NROW x 128 or null
    float* __restrict__ out_f32,             // N x 128 or null
    int N)
{
    __shared__ unsigned short As[64 * 128];   // 16 KB
    __shared__ unsigned short Bs[128 * 128];  // 32 KB

    const int tid  = threadIdx.x;
    const int wave = tid >> 6;
    const int lane = tid & 63;
    const int quad = lane >> 4;
    const int l16  = lane & 15;
    const int row0 = blockIdx.x * 64;

    f32x4 acc[4][2];
#pragma unroll
    for (int mt = 0; mt < 4; ++mt)
#pragma unroll
        for (int nt = 0; nt < 2; ++nt)
            acc[mt][nt] = (f32x4){0.f, 0.f, 0.f, 0.f};

    const int arow = lane >> 4;              // 0..3 row within 4-row issue
    const int acol = (lane & 15) * 8;        // element offset within row

#pragma unroll
    for (int kc = 0; kc < 8; ++kc) {
        // stage A chunk: 64 rows x 128 k'
        const unsigned short* asrc;
        int astr;
        if (kc < 7) { asrc = msg + (size_t)row0 * MS + kc * 128; astr = MS; }
        else        { asrc = hb  + (size_t)row0 * DD;            astr = DD; }
#pragma unroll
        for (int i = 0; i < 4; ++i) {
            int g = i * 4 + wave;            // 0..15 -> rows 4g..4g+3
            gl_lds16(asrc + (size_t)(g * 4 + arow) * astr + acol,
                     As + g * 512);
        }
        // stage B chunk: contiguous 32 KB
        const unsigned short* bsrc = Bw2l + (size_t)kc * DD * DD;
#pragma unroll
        for (int i = 0; i < 8; ++i) {
            int g = i * 4 + wave;            // 0..31
            gl_lds16(bsrc + (size_t)g * 512 + lane * 8,
                     Bs + g * 512);
        }
        __syncthreads();

        const unsigned short* As_l = As + l16 * 128;
        const unsigned short* Bs_l = Bs + (wave * 32 + l16) * 128;
#pragma unroll
        for (int kci = 0; kci < 4; ++kci) {
            int ko = kci * 32 + quad * 8;
            bf16x8 a0 = *(const bf16x8*)(As_l + 0 * 16 * 128 + ko);
            bf16x8 a1 = *(const bf16x8*)(As_l + 1 * 16 * 128 + ko);
            bf16x8 a2 = *(const bf16x8*)(As_l + 2 * 16 * 128 + ko);
            bf16x8 a3 = *(const bf16x8*)(As_l + 3 * 16 * 128 + ko);
            bf16x8 b0 = *(const bf16x8*)(Bs_l + 0 * 16 * 128 + ko);
            bf16x8 b1 = *(const bf16x8*)(Bs_l + 1 * 16 * 128 + ko);
            acc[0][0] = __builtin_amdgcn_mfma_f32_16x16x32_bf16(a0, b0, acc[0][0], 0, 0, 0);
            acc[1][0] = __builtin_amdgcn_mfma_f32_16x16x32_bf16(a1, b0, acc[1][0], 0, 0, 0);
            acc[2][0] = __builtin_amdgcn_mfma_f32_16x16x32_bf16(a2, b0, acc[2][0], 0, 0, 0);
            acc[3][0] = __builtin_amdgcn_mfma_f32_16x16x32_bf16(a3, b0, acc[3][0], 0, 0, 0);
            acc[0][1] = __builtin_amdgcn_mfma_f32_16x16x32_bf16(a0, b1, acc[0][1], 0, 0, 0);
            acc[1][1] = __builtin_amdgcn_mfma_f32_16x16x32_bf16(a1, b1, acc[1][1], 0, 0, 0);
            acc[2][1] = __builtin_amdgcn_mfma_f32_16x16x32_bf16(a2, b1, acc[2][1], 0, 0, 0);
            acc[3][1] = __builtin_amdgcn_mfma_f32_16x16x32_bf16(a3, b1, acc[3][1], 0, 0, 0);
        }
        __syncthreads();
    }

    const int ncol = wave * 32 + l16;
    float bias0 = br[ncol] + bl[ncol];
    float bias1 = br[ncol + 16] + bl[ncol + 16];
#pragma unroll
    for (int mt = 0; mt < 4; ++mt) {
#pragma unroll
        for (int reg = 0; reg < 4; ++reg) {
            int row = row0 + mt * 16 + quad * 4 + reg;
            if (row < N) {
                float v0 = fmaxf(acc[mt][0][reg] + bias0, 0.f);
                float v1 = fmaxf(acc[mt][1][reg] + bias1, 0.f);
                if (out_bf16) {
                    ushort2 p = pk2bf(v0, v1);
                    out_bf16[(size_t)row * DD + ncol]      = p.x;
                    out_bf16[(size_t)row * DD + ncol + 16] = p.y;
                }
                if (out_f32) {
                    out_f32[(size_t)row * DD + ncol]      = v0;
                    out_f32[(size_t)row * DD + ncol + 16] = v1;
                }
            }
        }
    }
}

// ---------------------------------------------------------------------------
// Graph segment sum: gf[n2g[n]] += nf[n] (n2g sorted).
// ---------------------------------------------------------------------------
__global__ __launch_bounds__(256) void graph_sum(
    const float* __restrict__ nf,
    const int* __restrict__ n2g,
    float* __restrict__ gf,
    int N)
{
    int t = blockIdx.x * 256 + threadIdx.x;
    int chunk = t >> 5;
    int lane = t & 31;
    int n0 = chunk * 16;
    if (n0 >= N) return;
    int nend = n0 + 16; if (nend > N) nend = N;

    float4 acc = make_float4(0.f, 0.f, 0.f, 0.f);
    int curg = n2g[n0];
    for (int n = n0; n < nend; ++n) {
        int g = n2g[n];
        if (g != curg) {
            float* dst = gf + (size_t)curg * DD + lane * 4;
            atomicAdd(dst + 0, acc.x); atomicAdd(dst + 1, acc.y);
            atomicAdd(dst + 2, acc.z); atomicAdd(dst + 3, acc.w);
            acc = make_float4(0.f, 0.f, 0.f, 0.f);
            curg = g;
        }
        float4 v = *(const float4*)(nf + (size_t)n * DD + lane * 4);
        acc.x += v.x; acc.y += v.y; acc.z += v.z; acc.w += v.w;
    }
    float* dst = gf + (size_t)curg * DD + lane * 4;
    atomicAdd(dst + 0, acc.x); atomicAdd(dst + 1, acc.y);
    atomicAdd(dst + 2, acc.z); atomicAdd(dst + 3, acc.w);
}

// ---------------------------------------------------------------------------
extern "C" void kernel_launch(void* const* d_in, const int* in_sizes, int n_in,
                              void* d_out, int out_size, void* d_ws, size_t ws_size,
                              hipStream_t stream)
{
    const float* x        = (const float*)d_in[0];
    const int*   node_in  = (const int*)d_in[1];
    const int*   node_out = (const int*)d_in[2];
    const int*   relation = (const int*)d_in[3];
    const float* ew       = (const float*)d_in[4];
    const int*   n2g      = (const int*)d_in[5];
    const float* Wr       = (const float*)d_in[6];
    const float* br       = (const float*)d_in[7];
    const float* Wl       = (const float*)d_in[8];
    const float* bl       = (const float*)d_in[9];

    float* out = (float*)d_out;
    float* gf = out;                 // 16 x 128
    float* nf = out + GG * DD;       // 30000 x 128

    // Workspace layout (~76 MB)
    char* w = (char*)d_ws;
    unsigned short* msg  = (unsigned short*)w; w += (size_t)NROW * MS * 2;      // 53.8 MB
    unsigned short* hbA  = (unsigned short*)w; w += (size_t)NROW * DD * 2;      // 7.7 MB
    unsigned short* hbB  = (unsigned short*)w; w += (size_t)NROW * DD * 2;      // 7.7 MB
    unsigned short* Bw2  = (unsigned short*)w; w += (size_t)LL * 8 * DD * DD * 2; // 0.79 MB
    int2*  meta   = (int2*)w;                  w += (size_t)NE * 8;             // 4.8 MB
    int2*  tmp    = (int2*)w;                  w += (size_t)NE * 8;             // 4.8 MB
    int*   start2 = (int*)w;                   w += (size_t)NROW * 8 * 4;       // 0.96 MB
    int*   bcnt   = (int*)w;                   w += (size_t)NB64 * 16 * 4 + 64;
    int*   bcur   = (int*)w;                   w += (size_t)NB64 * 16 * 4 + 64;
    int*   bstart = (int*)w;                   w += (size_t)(NB64 + 1) * 4 + 60;

    const int N = NN, E = NE;

    // ---- once per call: weight pack (+bcnt zero), x->bf16 (+gf zero), sort -
    pack_weights<<<(LL * 8 * DD * DD + 255) / 256, 256, 0, stream>>>(Wl, Wr, Bw2, bcnt);
    convert_bf16<<<(N * DD / 4 + 255) / 256, 256, 0, stream>>>(x, hbA, gf, N * DD / 4);

    bucket_hist<<<(E + 255) / 256, 256, 0, stream>>>(node_out, bcnt, E);
    bucket_scan<<<1, 512, 0, stream>>>(bcnt, bstart, bcur, NB64);
    bucket_scatter<<<(E + 255) / 256, 256, 0, stream>>>(
        node_in, node_out, relation, ew, bcur, tmp, E);
    bucket_sort<<<NB64, 256, 0, stream>>>(tmp, bstart, meta, start2, N);

    // ---- layers ----
    unsigned short* hin = hbA;
    unsigned short* hnext = hbB;
    for (int l = 0; l < LL; ++l) {
        const float* br_l = br + (size_t)l * DD;
        const float* bl_l = bl + (size_t)l * DD;
        const unsigned short* Bw2_l = Bw2 + (size_t)l * 8 * DD * DD;

        aggregate_msg<<<(N * 64 + 255) / 256, 256, 0, stream>>>(
            hin, start2, meta, msg, N);

        bool last = (l == LL - 1);
        gemm2<<<NB64, 256, 0, stream>>>(
            msg, hin, Bw2_l, br_l, bl_l,
            last ? (unsigned short*)nullptr : hnext,
            last ? nf : (float*)nullptr, N);

        unsigned short* t = hin; hin = hnext; hnext = t;
    }

    // ---- graph_feature ----
    int chunks = (N + 15) / 16;
    graph_sum<<<(chunks * 32 + 255) / 256, 256, 0, stream>>>(nf, n2g, gf, N);
}